// Round 7
// baseline (367.037 us; speedup 1.0000x reference)
//
#include <hip/hip_runtime.h>

constexpr int B = 32, C = 64, N = 8192, R = 32, R3 = R * R * R;
constexpr int QUART = R3 / 4;  // 8192 voxels -> 32 KB accum slab
constexpr int TP = 1024;       // prep block size
constexpr int TA = 512;        // accum block size (4 blocks/CU)
constexpr int PPTP = N / TP;   // prep points/thread = 8
constexpr int PPTA = N / TA;   // accum points/thread = 16

// native clang vectors (HIP's float4 is a struct; nontemporal builtins need
// true vector types)
typedef float f32x4 __attribute__((ext_vector_type(4)));
typedef unsigned int u32x4 __attribute__((ext_vector_type(4)));

// ---- workspace layout (~1.5 MB) -------------------------------------------
constexpr size_t IDX_OFF = 0;                            // B*N u16 (512 KB)
constexpr size_t PF_OFF  = (size_t)B * N * 2;            // B*N f32 (1 MB)

// LDS-only barrier: guards LDS hazards without the vmcnt(0) drain that
// __syncthreads() forces -- global stores (ncout/idx/voxout, exclusive
// regions never read in-kernel) stay in flight across it.
__device__ __forceinline__ void lds_barrier() {
  asm volatile("s_waitcnt lgkmcnt(0)" ::: "memory");
  __builtin_amdgcn_s_barrier();
  __builtin_amdgcn_sched_barrier(0);
}

// ---------------------------------------------------------------------------
// K1: fused per-batch prep (one block per batch). Round 7 changes:
//   - count grid (128 KB) + reduction scratch (28 KB) are now DISJOINT LDS
//     regions (156 KB total <= 160 KB/CU): the count-grid zero issues at
//     kernel start (hides under the mean loop's cold HBM loads) and its
//     visibility is covered by the reduction barriers -- no dedicated
//     zero phase, no aliasing barrier.
//   - the 3 sequential f64 mean trees (33 barriers) fuse into ONE 3-wide
//     tree (11 barriers). Per-component add ORDER is unchanged -> means
//     are bit-identical -> voxel assignment bit-identical.
// ---------------------------------------------------------------------------
__global__ __launch_bounds__(1024) void prep_kernel(
    const float* __restrict__ coords, float* __restrict__ ncout,
    unsigned short* __restrict__ idx, float* __restrict__ pf) {
  __shared__ unsigned int cnt[R3];     // 128 KB count grid
  __shared__ double sm3[3][TP];        // 24 KB mean-reduction scratch
  __shared__ float smf[TP];            // 4 KB max-reduction scratch

  const int b = blockIdx.x;
  const int t = threadIdx.x;
  const float* cb = coords + (size_t)b * 3 * N;

  // zero the count grid NOW -- overlaps the cold coord loads below; any
  // later __syncthreads makes the zeros visible before the atomics.
  {
    u32x4* cz = (u32x4*)cnt;
    const u32x4 z4 = {0u, 0u, 0u, 0u};
#pragma unroll
    for (int k = 0; k < R3 / 4; k += TP) cz[k + t] = z4;
  }

  // ---- mean (f64; per-component partial + tree order identical to all
  // prior rounds -> bit-identical means) ----
  double sx = 0.0, sy = 0.0, sz = 0.0;
  for (int n = t; n < N; n += TP) {
    sx += (double)cb[n];
    sy += (double)cb[N + n];
    sz += (double)cb[2 * N + n];
  }
  sm3[0][t] = sx;
  sm3[1][t] = sy;
  sm3[2][t] = sz;
  __syncthreads();
  for (int s = 512; s > 0; s >>= 1) {
    if (t < s) {
      sm3[0][t] += sm3[0][t + s];
      sm3[1][t] += sm3[1][t + s];
      sm3[2][t] += sm3[2][t + s];
    }
    __syncthreads();
  }
  float mean[3];
#pragma unroll
  for (int d = 0; d < 3; ++d) mean[d] = (float)(sm3[d][0] / (double)N);

  // ---- max point norm (f32; order matches np.linalg.norm) ----
  float mx = 0.0f;
  for (int n = t; n < N; n += TP) {
    float dx = __fsub_rn(cb[n], mean[0]);
    float dy = __fsub_rn(cb[N + n], mean[1]);
    float dz = __fsub_rn(cb[2 * N + n], mean[2]);
    float n2 = __fadd_rn(__fadd_rn(__fmul_rn(dx, dx), __fmul_rn(dy, dy)),
                         __fmul_rn(dz, dz));
    mx = fmaxf(mx, n2);
  }
  smf[t] = mx;
  __syncthreads();
  for (int s = 512; s > 0; s >>= 1) {
    if (t < s) smf[t] = fmaxf(smf[t], smf[t + s]);
    __syncthreads();
  }
  const float dn = __fmul_rn(__fsqrt_rn(smf[0]), 2.0f);  // EPS == 0

  // this thread's coord vector loads (L2-hot after the stats passes);
  // n0 = t*8: thread-contiguous points.
  const int n0 = t * PPTP;
  const f32x4 xa = *(const f32x4*)(cb + n0);
  const f32x4 xc = *(const f32x4*)(cb + n0 + 4);
  const f32x4 ya = *(const f32x4*)(cb + N + n0);
  const f32x4 yc = *(const f32x4*)(cb + N + n0 + 4);
  const f32x4 za = *(const f32x4*)(cb + 2 * N + n0);
  const f32x4 zc = *(const f32x4*)(cb + 2 * N + n0 + 4);

  // ---- voxelize: per-point math identical to prior rounds ----
  int iv[PPTP];
  f32x4 o0[2], o1[2], o2[2];
#pragma unroll
  for (int h = 0; h < 2; ++h) {
    const f32x4 xs = h ? xc : xa;
    const f32x4 ys = h ? yc : ya;
    const f32x4 zs = h ? zc : za;
#pragma unroll
    for (int j = 0; j < 4; ++j) {
      float t0 = __fmul_rn(__fadd_rn(__fdiv_rn(__fsub_rn(xs[j], mean[0]), dn), 0.5f), 32.0f);
      float t1 = __fmul_rn(__fadd_rn(__fdiv_rn(__fsub_rn(ys[j], mean[1]), dn), 0.5f), 32.0f);
      float t2 = __fmul_rn(__fadd_rn(__fdiv_rn(__fsub_rn(zs[j], mean[2]), dn), 0.5f), 32.0f);
      t0 = fminf(fmaxf(t0, 0.0f), 31.0f);
      t1 = fminf(fmaxf(t1, 0.0f), 31.0f);
      t2 = fminf(fmaxf(t2, 0.0f), 31.0f);
      o0[h][j] = t0;
      o1[h][j] = t1;
      o2[h][j] = t2;
      const int vx = (int)rintf(t0);  // half-to-even == np.round
      const int vy = (int)rintf(t1);
      const int vz = (int)rintf(t2);
      iv[h * 4 + j] = (vx * R + vy) * R + vz;  // [0, 32768)
    }
  }

  // ncout: pure output -> nontemporal vector stores
  float* nc = ncout + (size_t)b * 3 * N;
  __builtin_nontemporal_store(o0[0], (f32x4*)(nc + n0));
  __builtin_nontemporal_store(o0[1], (f32x4*)(nc + n0 + 4));
  __builtin_nontemporal_store(o1[0], (f32x4*)(nc + N + n0));
  __builtin_nontemporal_store(o1[1], (f32x4*)(nc + N + n0 + 4));
  __builtin_nontemporal_store(o2[0], (f32x4*)(nc + 2 * N + n0));
  __builtin_nontemporal_store(o2[1], (f32x4*)(nc + 2 * N + n0 + 4));

  // idx: packed u16x8 = one 16 B store (re-read by accum -> cached store)
  {
    u32x4 iw = {(unsigned)iv[0] | ((unsigned)iv[1] << 16),
                (unsigned)iv[2] | ((unsigned)iv[3] << 16),
                (unsigned)iv[4] | ((unsigned)iv[5] << 16),
                (unsigned)iv[6] | ((unsigned)iv[7] << 16)};
    *(u32x4*)(idx + (size_t)b * N + n0) = iw;
  }

  // count atomics (grid zeroed at kernel start; visibility via the
  // reduction barriers above)
#pragma unroll
  for (int k = 0; k < PPTP; ++k) atomicAdd(&cnt[iv[k]], 1u);
  lds_barrier();  // atomics complete; global stores stay in flight

  // ---- per-point reciprocal count from LDS (cached stores) ----
  f32x4 q0, q1;
#pragma unroll
  for (int j = 0; j < 4; ++j) {
    q0[j] = __fdiv_rn(1.0f, (float)cnt[iv[j]]);
    q1[j] = __fdiv_rn(1.0f, (float)cnt[iv[4 + j]]);
  }
  *(f32x4*)(pf + (size_t)b * N + n0) = q0;
  *(f32x4*)(pf + (size_t)b * N + n0 + 4) = q1;
}

// ---------------------------------------------------------------------------
// K2: one block per (b,c). ROUND 7: 512-thread blocks, 32 KB slab, 4 passes
// -> 4 blocks/CU (128 KB LDS, 32 waves; __launch_bounds__(512,8) caps VGPR
// at 64). Rationale: r5 (issue), r5 (cache hints), r6 (pipelining) were all
// null -- the last untested axis is independent store-streams per CU. The
// 6.3 TB/s harness fills run many small blocks/CU; we ran 2 big lockstep
// blocks. 4 finer blocks/CU = more independent streams, finer turnover.
// lgkm-only barriers keep dump stores in flight across pass boundaries.
// ---------------------------------------------------------------------------
__global__ __launch_bounds__(512, 8) void accum_kernel(
    const float* __restrict__ feats, const unsigned short* __restrict__ idx,
    const float* __restrict__ pf, float* __restrict__ voxout) {
  __shared__ float lds[QUART];  // 32 KB
  const int blk = blockIdx.x;  // b*C + c
  const int c = blk & (C - 1);
  const int b = blk >> 6;
  const int t = threadIdx.x;
  const int n0 = t * PPTA;  // 16 points, thread-contiguous

  const unsigned short* ib = idx + (size_t)b * N;
  const float* pb = pf + (size_t)b * N;
  const float* fb = feats + ((size_t)b * C + c) * N;

  int iv[PPTA];
  float fv[PPTA];
  // two load halves keep peak register pressure under the 64-VGPR cap
  {
    const u32x4 ip = *(const u32x4*)(ib + n0);
    const f32x4 p0 = *(const f32x4*)(pb + n0);
    const f32x4 p1 = *(const f32x4*)(pb + n0 + 4);
    const f32x4 f0 = __builtin_nontemporal_load((const f32x4*)(fb + n0));
    const f32x4 f1 = __builtin_nontemporal_load((const f32x4*)(fb + n0) + 1);
#pragma unroll
    for (int j = 0; j < 4; ++j) {
      iv[2 * j] = (int)(ip[j] & 0xffffu);
      iv[2 * j + 1] = (int)(ip[j] >> 16);
      fv[j] = f0[j] * p0[j];
      fv[4 + j] = f1[j] * p1[j];
    }
  }
  {
    const u32x4 ip = *(const u32x4*)(ib + n0 + 8);
    const f32x4 p0 = *(const f32x4*)(pb + n0 + 8);
    const f32x4 p1 = *(const f32x4*)(pb + n0 + 12);
    const f32x4 f0 = __builtin_nontemporal_load((const f32x4*)(fb + n0) + 2);
    const f32x4 f1 = __builtin_nontemporal_load((const f32x4*)(fb + n0) + 3);
#pragma unroll
    for (int j = 0; j < 4; ++j) {
      iv[8 + 2 * j] = (int)(ip[j] & 0xffffu);
      iv[8 + 2 * j + 1] = (int)(ip[j] >> 16);
      fv[8 + j] = f0[j] * p0[j];
      fv[12 + j] = f1[j] * p1[j];
    }
  }

  f32x4* lp = (f32x4*)lds;
  const f32x4 z = {0.f, 0.f, 0.f, 0.f};
  float* outb = voxout + ((size_t)b * C + c) * R3;

  for (int q = 0; q < 4; ++q) {
    const int lo = q * QUART;

    // zero the slab: QUART/4/TA = 4 f32x4 slots per thread
#pragma unroll
    for (int k = 0; k < 4; ++k) lp[t + k * TA] = z;
    lds_barrier();

    // scatter from registers (ds_add_f32; no global traffic)
#pragma unroll
    for (int k = 0; k < PPTA; ++k) {
      const int loc = iv[k] - lo;
      if ((unsigned)loc < (unsigned)QUART) atomicAdd(&lds[loc], fv[k]);
    }
    lds_barrier();

    // coalesced nontemporal dump of the exclusive 32 KB slice; stores left
    // in flight across the next barrier (exclusive region, lgkm-only sync)
    f32x4* ob4 = (f32x4*)(outb + lo);
#pragma unroll
    for (int k = 0; k < 4; ++k)
      __builtin_nontemporal_store(lp[t + k * TA], ob4 + t + k * TA);
    if (q < 3) lds_barrier();  // slab reused next pass
  }
}

extern "C" void kernel_launch(void* const* d_in, const int* in_sizes, int n_in,
                              void* d_out, int out_size, void* d_ws,
                              size_t ws_size, hipStream_t stream) {
  const float* feats  = (const float*)d_in[0];  // [B, C, N]
  const float* coords = (const float*)d_in[1];  // [B, 3, N]

  float* voxout = (float*)d_out;                // [B, C, R,R,R]
  float* ncout  = voxout + (size_t)B * C * R3;  // [B, 3, N]

  char* ws = (char*)d_ws;
  unsigned short* idx = (unsigned short*)(ws + IDX_OFF);
  float* pf           = (float*)(ws + PF_OFF);

  prep_kernel<<<B, TP, 0, stream>>>(coords, ncout, idx, pf);
  accum_kernel<<<B * C, TA, 0, stream>>>(feats, idx, pf, voxout);
}

// Round 9
// 366.653 us; speedup vs baseline: 1.0010x; 1.0010x over previous
//
#include <hip/hip_runtime.h>

constexpr int B = 32, C = 64, N = 8192, R = 32, R3 = R * R * R;
constexpr int QUART = R3 / 4;  // 8192 voxels -> 32 KB accum slab
constexpr int TP = 1024;       // prep block size
constexpr int TA = 512;        // accum block size (4 blocks/CU)
constexpr int PPTP = N / TP;   // prep points/thread = 8
constexpr int PPTA = N / TA;   // accum points/thread = 16

// native clang vectors (HIP's float4 is a struct; nontemporal builtins need
// true vector types)
typedef float f32x4 __attribute__((ext_vector_type(4)));
typedef unsigned int u32x4 __attribute__((ext_vector_type(4)));

// ---- workspace layout (~1.5 MB) -------------------------------------------
constexpr size_t IDX_OFF = 0;                            // B*N u16 (512 KB)
constexpr size_t PF_OFF  = (size_t)B * N * 2;            // B*N f32 (1 MB)

// LDS-only barrier: guards LDS hazards without the vmcnt(0) drain that
// __syncthreads() forces -- global stores (ncout/idx/voxout, exclusive
// regions never read in-kernel) stay in flight across it.
__device__ __forceinline__ void lds_barrier() {
  asm volatile("s_waitcnt lgkmcnt(0)" ::: "memory");
  __builtin_amdgcn_s_barrier();
  __builtin_amdgcn_sched_barrier(0);
}

// ---------------------------------------------------------------------------
// K1: fused per-batch prep (one block per batch). (r7 structure, restored
// after r8's cooperative-launch failure -- hipLaunchCooperativeKernel does
// not survive the harness's graph capture; output stayed memset-zero.)
//   - count grid (128 KB) + reduction scratch (28 KB) in DISJOINT LDS
//     regions (156 KB <= 160 KB/CU): count-grid zero issues at kernel start
//     and hides under the mean loop's cold HBM loads.
//   - single 3-wide f64 mean tree (11 barriers); per-component add order
//     identical to all prior rounds -> bit-identical means.
// ---------------------------------------------------------------------------
__global__ __launch_bounds__(1024) void prep_kernel(
    const float* __restrict__ coords, float* __restrict__ ncout,
    unsigned short* __restrict__ idx, float* __restrict__ pf) {
  __shared__ unsigned int cnt[R3];     // 128 KB count grid
  __shared__ double sm3[3][TP];        // 24 KB mean-reduction scratch
  __shared__ float smf[TP];            // 4 KB max-reduction scratch

  const int b = blockIdx.x;
  const int t = threadIdx.x;
  const float* cb = coords + (size_t)b * 3 * N;

  // zero the count grid NOW -- overlaps the cold coord loads below; any
  // later __syncthreads makes the zeros visible before the atomics.
  {
    u32x4* cz = (u32x4*)cnt;
    const u32x4 z4 = {0u, 0u, 0u, 0u};
#pragma unroll
    for (int k = 0; k < R3 / 4; k += TP) cz[k + t] = z4;
  }

  // ---- mean (f64; per-component partial + tree order identical to all
  // prior rounds -> bit-identical means) ----
  double sx = 0.0, sy = 0.0, sz = 0.0;
  for (int n = t; n < N; n += TP) {
    sx += (double)cb[n];
    sy += (double)cb[N + n];
    sz += (double)cb[2 * N + n];
  }
  sm3[0][t] = sx;
  sm3[1][t] = sy;
  sm3[2][t] = sz;
  __syncthreads();
  for (int s = 512; s > 0; s >>= 1) {
    if (t < s) {
      sm3[0][t] += sm3[0][t + s];
      sm3[1][t] += sm3[1][t + s];
      sm3[2][t] += sm3[2][t + s];
    }
    __syncthreads();
  }
  float mean[3];
#pragma unroll
  for (int d = 0; d < 3; ++d) mean[d] = (float)(sm3[d][0] / (double)N);

  // ---- max point norm (f32; order matches np.linalg.norm) ----
  float mx = 0.0f;
  for (int n = t; n < N; n += TP) {
    float dx = __fsub_rn(cb[n], mean[0]);
    float dy = __fsub_rn(cb[N + n], mean[1]);
    float dz = __fsub_rn(cb[2 * N + n], mean[2]);
    float n2 = __fadd_rn(__fadd_rn(__fmul_rn(dx, dx), __fmul_rn(dy, dy)),
                         __fmul_rn(dz, dz));
    mx = fmaxf(mx, n2);
  }
  smf[t] = mx;
  __syncthreads();
  for (int s = 512; s > 0; s >>= 1) {
    if (t < s) smf[t] = fmaxf(smf[t], smf[t + s]);
    __syncthreads();
  }
  const float dn = __fmul_rn(__fsqrt_rn(smf[0]), 2.0f);  // EPS == 0

  // this thread's coord vector loads (L2-hot after the stats passes);
  // n0 = t*8: thread-contiguous points.
  const int n0 = t * PPTP;
  const f32x4 xa = *(const f32x4*)(cb + n0);
  const f32x4 xc = *(const f32x4*)(cb + n0 + 4);
  const f32x4 ya = *(const f32x4*)(cb + N + n0);
  const f32x4 yc = *(const f32x4*)(cb + N + n0 + 4);
  const f32x4 za = *(const f32x4*)(cb + 2 * N + n0);
  const f32x4 zc = *(const f32x4*)(cb + 2 * N + n0 + 4);

  // ---- voxelize: per-point math identical to prior rounds ----
  int iv[PPTP];
  f32x4 o0[2], o1[2], o2[2];
#pragma unroll
  for (int h = 0; h < 2; ++h) {
    const f32x4 xs = h ? xc : xa;
    const f32x4 ys = h ? yc : ya;
    const f32x4 zs = h ? zc : za;
#pragma unroll
    for (int j = 0; j < 4; ++j) {
      float t0 = __fmul_rn(__fadd_rn(__fdiv_rn(__fsub_rn(xs[j], mean[0]), dn), 0.5f), 32.0f);
      float t1 = __fmul_rn(__fadd_rn(__fdiv_rn(__fsub_rn(ys[j], mean[1]), dn), 0.5f), 32.0f);
      float t2 = __fmul_rn(__fadd_rn(__fdiv_rn(__fsub_rn(zs[j], mean[2]), dn), 0.5f), 32.0f);
      t0 = fminf(fmaxf(t0, 0.0f), 31.0f);
      t1 = fminf(fmaxf(t1, 0.0f), 31.0f);
      t2 = fminf(fmaxf(t2, 0.0f), 31.0f);
      o0[h][j] = t0;
      o1[h][j] = t1;
      o2[h][j] = t2;
      const int vx = (int)rintf(t0);  // half-to-even == np.round
      const int vy = (int)rintf(t1);
      const int vz = (int)rintf(t2);
      iv[h * 4 + j] = (vx * R + vy) * R + vz;  // [0, 32768)
    }
  }

  // ncout: pure output -> nontemporal vector stores
  float* nc = ncout + (size_t)b * 3 * N;
  __builtin_nontemporal_store(o0[0], (f32x4*)(nc + n0));
  __builtin_nontemporal_store(o0[1], (f32x4*)(nc + n0 + 4));
  __builtin_nontemporal_store(o1[0], (f32x4*)(nc + N + n0));
  __builtin_nontemporal_store(o1[1], (f32x4*)(nc + N + n0 + 4));
  __builtin_nontemporal_store(o2[0], (f32x4*)(nc + 2 * N + n0));
  __builtin_nontemporal_store(o2[1], (f32x4*)(nc + 2 * N + n0 + 4));

  // idx: packed u16x8 = one 16 B store (re-read by accum -> cached store)
  {
    u32x4 iw = {(unsigned)iv[0] | ((unsigned)iv[1] << 16),
                (unsigned)iv[2] | ((unsigned)iv[3] << 16),
                (unsigned)iv[4] | ((unsigned)iv[5] << 16),
                (unsigned)iv[6] | ((unsigned)iv[7] << 16)};
    *(u32x4*)(idx + (size_t)b * N + n0) = iw;
  }

  // count atomics (grid zeroed at kernel start; visibility via the
  // reduction barriers above)
#pragma unroll
  for (int k = 0; k < PPTP; ++k) atomicAdd(&cnt[iv[k]], 1u);
  lds_barrier();  // atomics complete; global stores stay in flight

  // ---- per-point reciprocal count from LDS (cached stores) ----
  f32x4 q0, q1;
#pragma unroll
  for (int j = 0; j < 4; ++j) {
    q0[j] = __fdiv_rn(1.0f, (float)cnt[iv[j]]);
    q1[j] = __fdiv_rn(1.0f, (float)cnt[iv[4 + j]]);
  }
  *(f32x4*)(pf + (size_t)b * N + n0) = q0;
  *(f32x4*)(pf + (size_t)b * N + n0 + 4) = q1;
}

// ---------------------------------------------------------------------------
// K2: one block per (b,c). 512-thread blocks, 32 KB slab, 4 passes ->
// 4 blocks/CU (128 KB LDS, 32 waves; __launch_bounds__(512,8) caps VGPR at
// 64). Four structural experiments (issue width, cache policy, pipelining,
// granularity) were all null -- this accum is at its schedule-insensitive
// floor. lgkm-only barriers keep dump stores in flight across boundaries.
// ---------------------------------------------------------------------------
__global__ __launch_bounds__(512, 8) void accum_kernel(
    const float* __restrict__ feats, const unsigned short* __restrict__ idx,
    const float* __restrict__ pf, float* __restrict__ voxout) {
  __shared__ float lds[QUART];  // 32 KB
  const int blk = blockIdx.x;  // b*C + c
  const int c = blk & (C - 1);
  const int b = blk >> 6;
  const int t = threadIdx.x;
  const int n0 = t * PPTA;  // 16 points, thread-contiguous

  const unsigned short* ib = idx + (size_t)b * N;
  const float* pb = pf + (size_t)b * N;
  const float* fb = feats + ((size_t)b * C + c) * N;

  int iv[PPTA];
  float fv[PPTA];
  // two load halves keep peak register pressure under the 64-VGPR cap
  {
    const u32x4 ip = *(const u32x4*)(ib + n0);
    const f32x4 p0 = *(const f32x4*)(pb + n0);
    const f32x4 p1 = *(const f32x4*)(pb + n0 + 4);
    const f32x4 f0 = __builtin_nontemporal_load((const f32x4*)(fb + n0));
    const f32x4 f1 = __builtin_nontemporal_load((const f32x4*)(fb + n0) + 1);
#pragma unroll
    for (int j = 0; j < 4; ++j) {
      iv[2 * j] = (int)(ip[j] & 0xffffu);
      iv[2 * j + 1] = (int)(ip[j] >> 16);
      fv[j] = f0[j] * p0[j];
      fv[4 + j] = f1[j] * p1[j];
    }
  }
  {
    const u32x4 ip = *(const u32x4*)(ib + n0 + 8);
    const f32x4 p0 = *(const f32x4*)(pb + n0 + 8);
    const f32x4 p1 = *(const f32x4*)(pb + n0 + 12);
    const f32x4 f0 = __builtin_nontemporal_load((const f32x4*)(fb + n0) + 2);
    const f32x4 f1 = __builtin_nontemporal_load((const f32x4*)(fb + n0) + 3);
#pragma unroll
    for (int j = 0; j < 4; ++j) {
      iv[8 + 2 * j] = (int)(ip[j] & 0xffffu);
      iv[8 + 2 * j + 1] = (int)(ip[j] >> 16);
      fv[8 + j] = f0[j] * p0[j];
      fv[12 + j] = f1[j] * p1[j];
    }
  }

  f32x4* lp = (f32x4*)lds;
  const f32x4 z = {0.f, 0.f, 0.f, 0.f};
  float* outb = voxout + ((size_t)b * C + c) * R3;

  for (int q = 0; q < 4; ++q) {
    const int lo = q * QUART;

    // zero the slab: QUART/4/TA = 4 f32x4 slots per thread
#pragma unroll
    for (int k = 0; k < 4; ++k) lp[t + k * TA] = z;
    lds_barrier();

    // scatter from registers (ds_add_f32; no global traffic)
#pragma unroll
    for (int k = 0; k < PPTA; ++k) {
      const int loc = iv[k] - lo;
      if ((unsigned)loc < (unsigned)QUART) atomicAdd(&lds[loc], fv[k]);
    }
    lds_barrier();

    // coalesced nontemporal dump of the exclusive 32 KB slice; stores left
    // in flight across the next barrier (exclusive region, lgkm-only sync)
    f32x4* ob4 = (f32x4*)(outb + lo);
#pragma unroll
    for (int k = 0; k < 4; ++k)
      __builtin_nontemporal_store(lp[t + k * TA], ob4 + t + k * TA);
    if (q < 3) lds_barrier();  // slab reused next pass
  }
}

extern "C" void kernel_launch(void* const* d_in, const int* in_sizes, int n_in,
                              void* d_out, int out_size, void* d_ws,
                              size_t ws_size, hipStream_t stream) {
  const float* feats  = (const float*)d_in[0];  // [B, C, N]
  const float* coords = (const float*)d_in[1];  // [B, 3, N]

  float* voxout = (float*)d_out;                // [B, C, R,R,R]
  float* ncout  = voxout + (size_t)B * C * R3;  // [B, 3, N]

  char* ws = (char*)d_ws;
  unsigned short* idx = (unsigned short*)(ws + IDX_OFF);
  float* pf           = (float*)(ws + PF_OFF);

  prep_kernel<<<B, TP, 0, stream>>>(coords, ncout, idx, pf);
  accum_kernel<<<B * C, TA, 0, stream>>>(feats, idx, pf, voxout);
}